// Round 9
// baseline (141.603 us; speedup 1.0000x reference)
//
#include <hip/hip_runtime.h>
#include <hip/hip_fp16.h>
#include <math.h>

// 14-qubit batched statevector sim, MFMA engine. R9 = R8 (verified 95.2 us,
// no spill) + barrier restructuring ONLY:
//   - B-planes double-buffered (Bc0/Bc1); each U-build moved to AFTER the
//     previous pass's stores (out regs dead -> no R7 liveness spill; target
//     buffer last read >=2 barriers ago -> race-free). One barrier then
//     covers stores+build: removes 9 build barriers.
//   - zpart homed in Bc1 (idle since L4-B): removes the post-readout barrier.
// LDS: 65536 state + 2*2048 planes + 560 angles = 70192 B — R7 measured this
// exact footprint at 2 blocks/CU (occupancy 37.8%).
//
// Layouts (R7/R8-verified, per producer/consumer pair):
//   F32: phys = t*512 + ((128*(k>>3) + 8*mlow + (k&7)) ^ swz(t))
//   F_C: phys = tC*256 + ((128*((e>>3)&1) + 8*((e>>4)&15) + (e&7)) ^ swz(tC))
//   B-planes octet-major: physB(n,k) = 256*(k>>3) + 8*n + (k&7)
// All wave reads conflict-free; stores 4-way b64 (~floor for b64).
//
// Circuit mapping (R6-verified): pass = S' = S * U^T complex GEMM via
// v_mfma_f32_16x16x32_f16; U entries pure-real/pure-imag -> one signed plane
// + checkerboard split (s = topbit(n) ^ parity(8q)); index rotation per pass;
// ext-ctrl CNOT = B-address flip n^31/n^15; wrap CNOT(13,0) deferred; embed +
// L1-A closed-form rank-1 init; readout fused into last pass.

#define NQ 14
#define NLAYERS 4
#define NCLASSES 10
#define BLOCK 512

typedef _Float16 f16;
typedef _Float16 f16x8 __attribute__((ext_vector_type(8)));
typedef _Float16 f16x4 __attribute__((ext_vector_type(4)));
typedef float f32x4 __attribute__((ext_vector_type(4)));
typedef unsigned int u32;
typedef u32 u32x4 __attribute__((ext_vector_type(4)));

__device__ __forceinline__ f32x4 mf(f16x8 a, f16x8 b, f32x4 c) {
  return __builtin_amdgcn_mfma_f32_16x16x32_f16(a, b, c, 0, 0, 0);
}
__device__ __forceinline__ int swz(int t) { return ((t ^ (t >> 3)) & 7) << 3; }

__device__ __forceinline__ int finv5(int n) {
  n ^= ((n >> 3) & 1) << 4;
  n ^= ((n >> 2) & 1) << 3;
  n ^= ((n >> 1) & 1) << 2;
  n ^= (n & 1) << 1;
  return n;
}
__device__ __forceinline__ int finv3(int n) {
  n ^= ((n >> 2) & 1) << 3;
  n ^= ((n >> 1) & 1) << 2;
  n ^= (n & 1) << 1;
  return n;
}

// element j is REAL iff parity(j)==s; s = topbit(n) ^ parity(8q).
__device__ __forceinline__ void splitB(f16x8 b, int s, f16x8& br, f16x8& bi) {
  u32x4 u = __builtin_bit_cast(u32x4, b);
  const u32 m0 = s ? 0xFFFF0000u : 0x0000FFFFu;
  const u32 m1 = s ? 0x0000FFFFu : 0xFFFF0000u;
  u32x4 r;
  r[0] = u[0] & m0; r[1] = u[1] & m1; r[2] = u[2] & m1; r[3] = u[3] & m0;
  u32x4 ii;
  ii[0] = u[0] ^ r[0]; ii[1] = u[1] ^ r[1]; ii[2] = u[2] ^ r[2]; ii[3] = u[3] ^ r[3];
  br = __builtin_bit_cast(f16x8, r);
  bi = __builtin_bit_cast(f16x8, ii);
}

// 32x32 U-plane (RX on bits0-4 + 4-CNOT chain), octet-major storage.
__device__ __forceinline__ void build32(f16* Bc, const float* qc, const float* qs,
                                        int base, int tid) {
  const float c0 = qc[base], c1 = qc[base+1], c2 = qc[base+2], c3 = qc[base+3], c4 = qc[base+4];
  const float s0 = qs[base], s1 = qs[base+1], s2 = qs[base+2], s3 = qs[base+3], s4 = qs[base+4];
#pragma unroll
  for (int e = tid; e < 1024; e += BLOCK) {
    const int n = e >> 5, k = e & 31;
    const int d = finv5(n) ^ k;
    float mag = ((d & 1) ? s0 : c0) * ((d & 2) ? s1 : c1);
    mag *= ((d & 4) ? s2 : c2) * ((d & 8) ? s3 : c3);
    mag *= ((d & 16) ? s4 : c4);
    const int t = __popc(d) & 3;
    Bc[256 * (k >> 3) + 8 * n + (k & 7)] = (f16)((t == 1 || t == 2) ? -mag : mag);
  }
}
// 16-col C-plane (RX bits0-3 + 3-chain), k>=16 rows zero, octet-major.
__device__ __forceinline__ void buildC(f16* Bc, const float* qc, const float* qs,
                                       int base, int tid) {
  const float c0 = qc[base], c1 = qc[base+1], c2 = qc[base+2], c3 = qc[base+3];
  const float s0 = qs[base], s1 = qs[base+1], s2 = qs[base+2], s3 = qs[base+3];
  if (tid < 512) {
    const int n = tid >> 5, k = tid & 31;
    float v = 0.f;
    if (k < 16) {
      const int d = finv3(n) ^ k;
      float mag = ((d & 1) ? s0 : c0) * ((d & 2) ? s1 : c1);
      mag *= ((d & 4) ? s2 : c2) * ((d & 8) ? s3 : c3);
      const int t = __popc(d) & 3;
      v = (t == 1 || t == 2) ? -mag : mag;
    }
    Bc[256 * (k >> 3) + 8 * n + (k & 7)] = (f16)v;
  }
}

// 5-wire GEMM pass. STORE_C: store into F_C (B-phase) else F32 (A-phase).
template<bool CTRL, bool STORE_C>
__device__ __forceinline__ void pass32(f16* __restrict__ reP, f16* __restrict__ imP,
                                       const f16* __restrict__ BcR, int tid) {
  const int lane = tid & 63, wave = tid >> 6;
  const int q = lane >> 4, cc = lane & 15;
  int n0 = cc, n1 = cc | 16;
  if (CTRL && wave >= 4) { n0 ^= 31; n1 ^= 31; }
  const int pq = (0x6 >> q) & 1;
  f16x8 br0, bi0, br1, bi1;
  {
    const f16x8 b0 = *(const f16x8*)(BcR + 256 * q + 8 * n0);
    const f16x8 b1 = *(const f16x8*)(BcR + 256 * q + 8 * n1);
    splitB(b0, ((n0 >> 4) ^ pq) & 1, br0, bi0);
    splitB(b1, ((n1 >> 4) ^ pq) & 1, br1, bi1);
  }
  f16x4 outR[8], outI[8];
#pragma unroll
  for (int i = 0; i < 4; ++i) {
    const int mt = wave * 4 + i;
    const int pA = mt * 512 + ((128 * q + 8 * cc) ^ swz(mt));
    const f16x8 Ar = *(const f16x8*)(reP + pA);
    const f16x8 Ai = *(const f16x8*)(imP + pA);
    const f16x8 nAi = -Ai;
    {
      f32x4 aR = {0.f,0.f,0.f,0.f}, aI = {0.f,0.f,0.f,0.f};
      aR = mf(Ar, br0, aR); aR = mf(nAi, bi0, aR);
      aI = mf(Ar, bi0, aI); aI = mf(Ai, br0, aI);
      outR[i * 2 + 0] = __builtin_convertvector(aR, f16x4);
      outI[i * 2 + 0] = __builtin_convertvector(aI, f16x4);
    }
    {
      f32x4 aR = {0.f,0.f,0.f,0.f}, aI = {0.f,0.f,0.f,0.f};
      aR = mf(Ar, br1, aR); aR = mf(nAi, bi1, aR);
      aI = mf(Ar, bi1, aI); aI = mf(Ai, br1, aI);
      outR[i * 2 + 1] = __builtin_convertvector(aR, f16x4);
      outI[i * 2 + 1] = __builtin_convertvector(aI, f16x4);
    }
  }
  __syncthreads();   // all reads done before in-place permuted writes
#pragma unroll
  for (int i = 0; i < 4; ++i) {
    const int mt = wave * 4 + i;
#pragma unroll
    for (int nt = 0; nt < 2; ++nt) {
      const int n5 = nt * 16 + cc;
      int pS;
      if constexpr (STORE_C) {
        const int tC = (mt >> 4) + 2 * n5;
        pS = tC * 256 + ((128 * (q >> 1) + 8 * (mt & 15) + 4 * (q & 1)) ^ swz(tC));
      } else {
        pS = n5 * 512 + ((128 * (2 * (mt & 1) + (q >> 1)) + 8 * (mt >> 1) + 4 * (q & 1)) ^ swz(n5));
      }
      *(f16x4*)(reP + pS) = outR[i * 2 + nt];
      *(f16x4*)(imP + pS) = outI[i * 2 + nt];
    }
  }
}

// 4-wire pass C (K padded to 32). Ext-ctrl (9,10) always; wrap CNOT(13,0) =
// reg-pair swap at store / p-swap at readout (ctrl = cc bit3).
template<bool FINAL>
__device__ __forceinline__ void passC(f16* __restrict__ reP, f16* __restrict__ imP,
                                      const f16* __restrict__ BcR, int tid,
                                      float* __restrict__ zloc) {
  const int lane = tid & 63, wave = tid >> 6;
  const int q = lane >> 4, cc = lane & 15;
  int n0 = cc;
  if (wave >= 4) n0 ^= 15;
  const int pq = (0x6 >> q) & 1;
  f16x8 br, bi;
  {
    const f16x8 b = *(const f16x8*)(BcR + 256 * q + 8 * n0);
    splitB(b, ((n0 >> 3) ^ pq) & 1, br, bi);
  }
  f16x4 outR[8], outI[8];
#pragma unroll
  for (int i = 0; i < 8; ++i) {
    const int mtC = wave * 8 + i;
    const int pA = mtC * 256 + ((128 * (q & 1) + 8 * cc) ^ swz(mtC));
    const f16x8 Ar = *(const f16x8*)(reP + pA);
    const f16x8 Ai = *(const f16x8*)(imP + pA);
    const f16x8 nAi = -Ai;
    f32x4 aR = {0.f,0.f,0.f,0.f}, aI = {0.f,0.f,0.f,0.f};
    aR = mf(Ar, br, aR); aR = mf(nAi, bi, aR);
    aI = mf(Ar, bi, aI); aI = mf(Ai, br, aI);
    if constexpr (FINAL) {
      float p0 = aR[0]*aR[0] + aI[0]*aI[0];
      float p1 = aR[1]*aR[1] + aI[1]*aI[1];
      float p2 = aR[2]*aR[2] + aI[2]*aI[2];
      float p3 = aR[3]*aR[3] + aI[3]*aI[3];
      if (cc & 8) { float t = p0; p0 = p1; p1 = t; t = p2; p2 = p3; p3 = t; }
      const float ps = p0 + p1 + p2 + p3;
      zloc[0] += (p0 - p1) + (p2 - p3);
      zloc[1] += (p0 + p1) - (p2 + p3);
      zloc[2] += (q & 1) ? -ps : ps;
      zloc[3] += (q & 2) ? -ps : ps;
#pragma unroll
      for (int w = 0; w < 6; ++w) zloc[4 + w] += ((mtC >> w) & 1) ? -ps : ps;
#pragma unroll
      for (int w = 0; w < 4; ++w) zloc[10 + w] += ((cc >> w) & 1) ? -ps : ps;
    } else {
      if (cc & 8) {
        f32x4 tR = aR, tI = aI;
        aR[0] = tR[1]; aR[1] = tR[0]; aR[2] = tR[3]; aR[3] = tR[2];
        aI[0] = tI[1]; aI[1] = tI[0]; aI[2] = tI[3]; aI[3] = tI[2];
      }
      outR[i] = __builtin_convertvector(aR, f16x4);
      outI[i] = __builtin_convertvector(aI, f16x4);
    }
  }
  if constexpr (!FINAL) {
    __syncthreads();
#pragma unroll
    for (int i = 0; i < 8; ++i) {
      const int mtC = wave * 8 + i;
      const int tP = 2 * cc + (mtC >> 5);
      const int pS = tP * 512 +
          ((128 * (2 * (mtC & 1) + (q >> 1)) + 8 * ((mtC >> 1) & 15) + 4 * (q & 1)) ^ swz(tP));
      *(f16x4*)(reP + pS) = outR[i];
      *(f16x4*)(imP + pS) = outI[i];
    }
  }
}

__global__ __launch_bounds__(BLOCK, 4) void qsim_kernel(
    const float* __restrict__ x, const float* __restrict__ qp,
    const float* __restrict__ fcw, const float* __restrict__ fcb,
    float* __restrict__ out) {
  extern __shared__ unsigned char smem[];
  f16* reP = (f16*)smem;                    // [16384]
  f16* imP = reP + 16384;                   // [16384]
  f16* Bc0 = imP + 16384;                   // [1024]
  f16* Bc1 = Bc0 + 1024;                    // [1024] (aliased init scratch/zpart)
  float* qc = (float*)(Bc1 + 1024);         // [56]
  float* qs = qc + 56;                      // [56]
  float* xc = qs + 56;                      // [14]
  float* xs = xc + 14;                      // [14]

  const int b = blockIdx.x;
  const int tid = threadIdx.x;

  // ---- angles ----
  if (tid < NQ) {
    float sv, cv; sincosf(0.5f * x[b * NQ + tid], &sv, &cv);
    xc[tid] = cv; xs[tid] = sv;
  } else if (tid >= 64 && tid < 64 + NLAYERS * NQ) {
    const int k = tid - 64;
    float sv, cv; sincosf(0.5f * qp[k], &sv, &cv);
    qc[k] = cv; qs[k] = sv;
  }
  __syncthreads();

  // ---- closed-form state at L1-B entry (scratch aliases Bc1) ----
  float* Flo  = (float*)Bc1;        // [32]
  float* psi  = Flo + 32;           // [32]
  float* PsiR = psi + 32;           // [32]
  float* PsiI = PsiR + 32;          // [32]
  if (tid < 32) {
    float f = 1.f;
#pragma unroll
    for (int j = 0; j < 5; ++j) f *= ((tid >> j) & 1) ? xs[5 + j] : xc[5 + j];
    Flo[tid] = f;
  } else if (tid < 64) {
    const int k = tid - 32;
    float f = 1.f;
#pragma unroll
    for (int j = 0; j < 5; ++j) f *= ((k >> j) & 1) ? xs[j] : xc[j];
    psi[k] = f;
  }
  __syncthreads();
  if (tid < 32) {   // Psi = U_L1A * psi
    const float c0 = qc[0], c1 = qc[1], c2 = qc[2], c3 = qc[3], c4 = qc[4];
    const float s0 = qs[0], s1 = qs[1], s2 = qs[2], s3 = qs[3], s4 = qs[4];
    const int a = finv5(tid);
    float ar = 0.f, ai = 0.f;
    for (int k = 0; k < 32; ++k) {
      const int d = a ^ k;
      float mag = ((d & 1) ? s0 : c0) * ((d & 2) ? s1 : c1);
      mag *= ((d & 4) ? s2 : c2) * ((d & 8) ? s3 : c3);
      mag *= ((d & 16) ? s4 : c4);
      mag *= psi[k];
      const int t = __popc(d) & 3;
      if (t == 0) ar += mag; else if (t == 1) ai -= mag;
      else if (t == 2) ar -= mag; else ai += mag;
    }
    PsiR[tid] = ar; PsiI[tid] = ai;
  }
  __syncthreads();
  {  // state at L1-B entry: amp(e = tid*32 + k) -> F32 layout
    float fhi = 1.f;
#pragma unroll
    for (int j = 0; j < 4; ++j) fhi *= ((tid >> j) & 1) ? xs[10 + j] : xc[10 + j];
    const float cr = fhi * PsiR[tid >> 4], ci = fhi * PsiI[tid >> 4];
    const int t = tid >> 4;
    const int sz = swz(t);
    float Fl[32];
#pragma unroll
    for (int j = 0; j < 32; ++j) Fl[j] = Flo[j];
    __syncthreads();   // scratch reads done
#pragma unroll
    for (int kb = 0; kb < 4; ++kb) {
      f16x8 hr, hi;
#pragma unroll
      for (int j = 0; j < 8; ++j) {
        const float F = Fl[8 * kb + j];
        hr[j] = (f16)(F * cr);
        hi[j] = (f16)(F * ci);
      }
      const int pb = t * 512 + ((128 * kb + 8 * (tid & 15)) ^ sz);
      *(f16x8*)(reP + pb) = hr;
      *(f16x8*)(imP + pb) = hi;
    }
  }
  build32(Bc0, qc, qs, 0 * NQ + 5, tid);   // U(L1-B)
  __syncthreads();

  // ---- 11 GEMM passes; build for pass p+1 after pass p's stores, then one
  // barrier covers stores+build (buffers alternate Bc0/Bc1) ----
  pass32<true, true>(reP, imP, Bc0, tid);     // L1-B
  buildC (Bc1, qc, qs, 0 * NQ + 10, tid);
  __syncthreads();
  passC<false>(reP, imP, Bc1, tid, nullptr);  // L1-C
  build32(Bc0, qc, qs, 1 * NQ + 0, tid);
  __syncthreads();
  pass32<false, false>(reP, imP, Bc0, tid);   // L2-A
  build32(Bc1, qc, qs, 1 * NQ + 5, tid);
  __syncthreads();
  pass32<true, true>(reP, imP, Bc1, tid);     // L2-B
  buildC (Bc0, qc, qs, 1 * NQ + 10, tid);
  __syncthreads();
  passC<false>(reP, imP, Bc0, tid, nullptr);  // L2-C
  build32(Bc1, qc, qs, 2 * NQ + 0, tid);
  __syncthreads();
  pass32<false, false>(reP, imP, Bc1, tid);   // L3-A
  build32(Bc0, qc, qs, 2 * NQ + 5, tid);
  __syncthreads();
  pass32<true, true>(reP, imP, Bc0, tid);     // L3-B
  buildC (Bc1, qc, qs, 2 * NQ + 10, tid);
  __syncthreads();
  passC<false>(reP, imP, Bc1, tid, nullptr);  // L3-C
  build32(Bc0, qc, qs, 3 * NQ + 0, tid);
  __syncthreads();
  pass32<false, false>(reP, imP, Bc0, tid);   // L4-A
  build32(Bc1, qc, qs, 3 * NQ + 5, tid);
  __syncthreads();
  pass32<true, true>(reP, imP, Bc1, tid);     // L4-B
  buildC (Bc0, qc, qs, 3 * NQ + 10, tid);
  __syncthreads();

  float zloc[NQ];
#pragma unroll
  for (int w = 0; w < NQ; ++w) zloc[w] = 0.f;
  passC<true>(reP, imP, Bc0, tid, zloc);      // L4-C fused readout (no stores)

  // ---- reduce + linear head; zpart in Bc1 (idle since L4-B) -> no barrier
  // needed between readout and zpart writes ----
  float* zpart = (float*)Bc1;        // [8*14]
  float* zbuf  = zpart + 112;        // [14]
#pragma unroll
  for (int w = 0; w < NQ; ++w) {
#pragma unroll
    for (int off = 32; off > 0; off >>= 1)
      zloc[w] += __shfl_down(zloc[w], off, 64);
  }
  const int wave = tid >> 6, lane = tid & 63;
  if (lane == 0) {
#pragma unroll
    for (int w = 0; w < NQ; ++w) zpart[wave * NQ + w] = zloc[w];
  }
  __syncthreads();
  if (tid < NQ) {
    float a = 0.f;
#pragma unroll
    for (int v = 0; v < 8; ++v) a += zpart[v * NQ + tid];
    zbuf[tid] = a;
  }
  __syncthreads();
  if (tid < NCLASSES) {
    float acc = fcb[tid];
#pragma unroll
    for (int w = 0; w < NQ; ++w) acc = fmaf(zbuf[w], fcw[tid * NQ + w], acc);
    out[b * NCLASSES + tid] = acc;
  }
}

extern "C" void kernel_launch(void* const* d_in, const int* in_sizes, int n_in,
                              void* d_out, int out_size, void* d_ws, size_t ws_size,
                              hipStream_t stream) {
  const float* x   = (const float*)d_in[0];
  const float* qp  = (const float*)d_in[1];
  const float* fcw = (const float*)d_in[2];
  const float* fcb = (const float*)d_in[3];
  float* out = (float*)d_out;
  const int B = in_sizes[0] / NQ;

  const size_t shmem = (size_t)(2 * 16384 + 2 * 1024) * sizeof(f16)
                     + (size_t)(56 + 56 + 14 + 14) * sizeof(float);   // 70192 B
  (void)hipFuncSetAttribute((const void*)qsim_kernel,
                            hipFuncAttributeMaxDynamicSharedMemorySize, (int)shmem);
  qsim_kernel<<<B, BLOCK, shmem, stream>>>(x, qp, fcw, fcb, out);
}

// Round 10
// 139.674 us; speedup vs baseline: 1.0138x; 1.0138x over previous
//
#include <hip/hip_runtime.h>
#include <hip/hip_fp16.h>
#include <math.h>

// 14-qubit batched statevector sim, MFMA engine. R10 = R8 skeleton (95.2 us,
// verified: no spill, single Bc, builds as separate steps) + VALU diet:
//   1) f32->f16 output conversion via v_cvt_pkrtz_f16_f32 (2 ops per f16x4
//      instead of 4 cvt + 2 pack)  -- ~64 VALU/thread/pass saved.
//   2) U-planes pre-split at build time into signed real + imag planes
//      (checkerboard t&1, same parity algebra verified in R6) -> splitB and
//      its 16 bitops deleted from every pass; +2 cheap b128 B-reads instead.
// R9's barrier removal was neutral->reverted; R8 bracket structure kept.
//
// Layouts (R7/R8-verified):
//   F32: phys = t*512 + ((128*(k>>3) + 8*mlow + (k&7)) ^ swz(t))
//   F_C: phys = tC*256 + ((128*((e>>3)&1) + 8*((e>>4)&15) + (e&7)) ^ swz(tC))
//   B-planes octet-major: re at 256*(k>>3)+8*n+(k&7), im at +1024.
// All wave reads conflict-free; stores 4-way b64 (b64 BW floor).
// LDS: 65536 state + 4096 Bc(2 planes) + 560 angles = 70192 B (R7/R9 measured
// this exact footprint at 2 blocks/CU).
//
// Circuit mapping (R6-verified): pass = S' = S * U^T complex GEMM via
// v_mfma_f32_16x16x32_f16; index rotation per pass; ext-ctrl CNOT = B-address
// flip n^31/n^15; wrap CNOT(13,0) deferred; embed + L1-A closed-form rank-1
// init; readout fused into last pass.

#define NQ 14
#define NLAYERS 4
#define NCLASSES 10
#define BLOCK 512

typedef _Float16 f16;
typedef _Float16 f16x2 __attribute__((ext_vector_type(2)));
typedef _Float16 f16x8 __attribute__((ext_vector_type(8)));
typedef _Float16 f16x4 __attribute__((ext_vector_type(4)));
typedef float f32x4 __attribute__((ext_vector_type(4)));
typedef unsigned int u32;
typedef u32 u32x2 __attribute__((ext_vector_type(2)));

__device__ __forceinline__ f32x4 mf(f16x8 a, f16x8 b, f32x4 c) {
  return __builtin_amdgcn_mfma_f32_16x16x32_f16(a, b, c, 0, 0, 0);
}
__device__ __forceinline__ int swz(int t) { return ((t ^ (t >> 3)) & 7) << 3; }

// packed f32x4 -> f16x4 (2x v_cvt_pkrtz_f16_f32)
__device__ __forceinline__ f16x4 cvt4(f32x4 v) {
  u32x2 r;
  r[0] = __builtin_bit_cast(u32, __builtin_amdgcn_cvt_pkrtz(v[0], v[1]));
  r[1] = __builtin_bit_cast(u32, __builtin_amdgcn_cvt_pkrtz(v[2], v[3]));
  return __builtin_bit_cast(f16x4, r);
}

__device__ __forceinline__ int finv5(int n) {
  n ^= ((n >> 3) & 1) << 4;
  n ^= ((n >> 2) & 1) << 3;
  n ^= ((n >> 1) & 1) << 2;
  n ^= (n & 1) << 1;
  return n;
}
__device__ __forceinline__ int finv3(int n) {
  n ^= ((n >> 2) & 1) << 3;
  n ^= ((n >> 1) & 1) << 2;
  n ^= (n & 1) << 1;
  return n;
}

// 32x32 U (RX bits0-4 + 4-CNOT chain), pre-split: re plane [0,1024), im [1024,2048).
// Entry (n,k) value (-i)^t * mag with t = popc(d)&3, d = finv5(n)^k: real iff t even.
__device__ __forceinline__ void build32(f16* Bc, const float* qc, const float* qs,
                                        int base, int tid) {
  const float c0 = qc[base], c1 = qc[base+1], c2 = qc[base+2], c3 = qc[base+3], c4 = qc[base+4];
  const float s0 = qs[base], s1 = qs[base+1], s2 = qs[base+2], s3 = qs[base+3], s4 = qs[base+4];
#pragma unroll
  for (int e = tid; e < 1024; e += BLOCK) {
    const int n = e >> 5, k = e & 31;
    const int d = finv5(n) ^ k;
    float mag = ((d & 1) ? s0 : c0) * ((d & 2) ? s1 : c1);
    mag *= ((d & 4) ? s2 : c2) * ((d & 8) ? s3 : c3);
    mag *= ((d & 16) ? s4 : c4);
    const int t = __popc(d) & 3;
    const f16 v = (f16)((t == 1 || t == 2) ? -mag : mag);
    const int p = 256 * (k >> 3) + 8 * n + (k & 7);
    const bool isreal = !(t & 1);
    Bc[p]        = isreal ? v : (f16)0.f;
    Bc[p + 1024] = isreal ? (f16)0.f : v;
  }
}
// 16-col C-plane (RX bits0-3 + 3-chain), k>=16 zero, pre-split like build32.
__device__ __forceinline__ void buildC(f16* Bc, const float* qc, const float* qs,
                                       int base, int tid) {
  const float c0 = qc[base], c1 = qc[base+1], c2 = qc[base+2], c3 = qc[base+3];
  const float s0 = qs[base], s1 = qs[base+1], s2 = qs[base+2], s3 = qs[base+3];
  const int n = tid >> 5, k = tid & 31;
  f16 vr = (f16)0.f, vi = (f16)0.f;
  if (k < 16) {
    const int d = finv3(n) ^ k;
    float mag = ((d & 1) ? s0 : c0) * ((d & 2) ? s1 : c1);
    mag *= ((d & 4) ? s2 : c2) * ((d & 8) ? s3 : c3);
    const int t = __popc(d) & 3;
    const f16 v = (f16)((t == 1 || t == 2) ? -mag : mag);
    if (t & 1) vi = v; else vr = v;
  }
  const int p = 256 * (k >> 3) + 8 * n + (k & 7);
  Bc[p]        = vr;
  Bc[p + 1024] = vi;
}

// 5-wire GEMM pass. STORE_C: store into F_C (B-phase) else F32 (A-phase).
template<bool CTRL, bool STORE_C>
__device__ __forceinline__ void pass32(f16* __restrict__ reP, f16* __restrict__ imP,
                                       const f16* __restrict__ BcR, int tid) {
  const int lane = tid & 63, wave = tid >> 6;
  const int q = lane >> 4, cc = lane & 15;
  int n0 = cc, n1 = cc | 16;
  if (CTRL && wave >= 4) { n0 ^= 31; n1 ^= 31; }
  const f16x8 br0 = *(const f16x8*)(BcR + 256 * q + 8 * n0);
  const f16x8 bi0 = *(const f16x8*)(BcR + 1024 + 256 * q + 8 * n0);
  const f16x8 br1 = *(const f16x8*)(BcR + 256 * q + 8 * n1);
  const f16x8 bi1 = *(const f16x8*)(BcR + 1024 + 256 * q + 8 * n1);
  f16x4 outR[8], outI[8];
#pragma unroll
  for (int i = 0; i < 4; ++i) {
    const int mt = wave * 4 + i;
    const int pA = mt * 512 + ((128 * q + 8 * cc) ^ swz(mt));
    const f16x8 Ar = *(const f16x8*)(reP + pA);
    const f16x8 Ai = *(const f16x8*)(imP + pA);
    const f16x8 nAi = -Ai;
    {
      f32x4 aR = {0.f,0.f,0.f,0.f}, aI = {0.f,0.f,0.f,0.f};
      aR = mf(Ar, br0, aR); aR = mf(nAi, bi0, aR);
      aI = mf(Ar, bi0, aI); aI = mf(Ai, br0, aI);
      outR[i * 2 + 0] = cvt4(aR);
      outI[i * 2 + 0] = cvt4(aI);
    }
    {
      f32x4 aR = {0.f,0.f,0.f,0.f}, aI = {0.f,0.f,0.f,0.f};
      aR = mf(Ar, br1, aR); aR = mf(nAi, bi1, aR);
      aI = mf(Ar, bi1, aI); aI = mf(Ai, br1, aI);
      outR[i * 2 + 1] = cvt4(aR);
      outI[i * 2 + 1] = cvt4(aI);
    }
  }
  __syncthreads();   // all reads done before in-place permuted writes
#pragma unroll
  for (int i = 0; i < 4; ++i) {
    const int mt = wave * 4 + i;
#pragma unroll
    for (int nt = 0; nt < 2; ++nt) {
      const int n5 = nt * 16 + cc;
      int pS;
      if constexpr (STORE_C) {
        const int tC = (mt >> 4) + 2 * n5;
        pS = tC * 256 + ((128 * (q >> 1) + 8 * (mt & 15) + 4 * (q & 1)) ^ swz(tC));
      } else {
        pS = n5 * 512 + ((128 * (2 * (mt & 1) + (q >> 1)) + 8 * (mt >> 1) + 4 * (q & 1)) ^ swz(n5));
      }
      *(f16x4*)(reP + pS) = outR[i * 2 + nt];
      *(f16x4*)(imP + pS) = outI[i * 2 + nt];
    }
  }
}

// 4-wire pass C (K padded to 32). Ext-ctrl (9,10) always; wrap CNOT(13,0) =
// reg-pair swap at store / p-swap at readout (ctrl = cc bit3).
template<bool FINAL>
__device__ __forceinline__ void passC(f16* __restrict__ reP, f16* __restrict__ imP,
                                      const f16* __restrict__ BcR, int tid,
                                      float* __restrict__ zloc) {
  const int lane = tid & 63, wave = tid >> 6;
  const int q = lane >> 4, cc = lane & 15;
  int n0 = cc;
  if (wave >= 4) n0 ^= 15;
  const f16x8 br = *(const f16x8*)(BcR + 256 * q + 8 * n0);
  const f16x8 bi = *(const f16x8*)(BcR + 1024 + 256 * q + 8 * n0);
  f16x4 outR[8], outI[8];
#pragma unroll
  for (int i = 0; i < 8; ++i) {
    const int mtC = wave * 8 + i;
    const int pA = mtC * 256 + ((128 * (q & 1) + 8 * cc) ^ swz(mtC));
    const f16x8 Ar = *(const f16x8*)(reP + pA);
    const f16x8 Ai = *(const f16x8*)(imP + pA);
    const f16x8 nAi = -Ai;
    f32x4 aR = {0.f,0.f,0.f,0.f}, aI = {0.f,0.f,0.f,0.f};
    aR = mf(Ar, br, aR); aR = mf(nAi, bi, aR);
    aI = mf(Ar, bi, aI); aI = mf(Ai, br, aI);
    if constexpr (FINAL) {
      float p0 = aR[0]*aR[0] + aI[0]*aI[0];
      float p1 = aR[1]*aR[1] + aI[1]*aI[1];
      float p2 = aR[2]*aR[2] + aI[2]*aI[2];
      float p3 = aR[3]*aR[3] + aI[3]*aI[3];
      if (cc & 8) { float t = p0; p0 = p1; p1 = t; t = p2; p2 = p3; p3 = t; }
      const float ps = p0 + p1 + p2 + p3;
      zloc[0] += (p0 - p1) + (p2 - p3);
      zloc[1] += (p0 + p1) - (p2 + p3);
      zloc[2] += (q & 1) ? -ps : ps;
      zloc[3] += (q & 2) ? -ps : ps;
#pragma unroll
      for (int w = 0; w < 6; ++w) zloc[4 + w] += ((mtC >> w) & 1) ? -ps : ps;
#pragma unroll
      for (int w = 0; w < 4; ++w) zloc[10 + w] += ((cc >> w) & 1) ? -ps : ps;
    } else {
      if (cc & 8) {
        f32x4 tR = aR, tI = aI;
        aR[0] = tR[1]; aR[1] = tR[0]; aR[2] = tR[3]; aR[3] = tR[2];
        aI[0] = tI[1]; aI[1] = tI[0]; aI[2] = tI[3]; aI[3] = tI[2];
      }
      outR[i] = cvt4(aR);
      outI[i] = cvt4(aI);
    }
  }
  if constexpr (!FINAL) {
    __syncthreads();
#pragma unroll
    for (int i = 0; i < 8; ++i) {
      const int mtC = wave * 8 + i;
      const int tP = 2 * cc + (mtC >> 5);
      const int pS = tP * 512 +
          ((128 * (2 * (mtC & 1) + (q >> 1)) + 8 * ((mtC >> 1) & 15) + 4 * (q & 1)) ^ swz(tP));
      *(f16x4*)(reP + pS) = outR[i];
      *(f16x4*)(imP + pS) = outI[i];
    }
  }
}

__global__ __launch_bounds__(BLOCK, 4) void qsim_kernel(
    const float* __restrict__ x, const float* __restrict__ qp,
    const float* __restrict__ fcw, const float* __restrict__ fcb,
    float* __restrict__ out) {
  extern __shared__ unsigned char smem[];
  f16* reP = (f16*)smem;                    // [16384]
  f16* imP = reP + 16384;                   // [16384]
  f16* Bc  = imP + 16384;                   // [2048] re+im planes (aliased scratch)
  float* qc = (float*)(Bc + 2048);          // [56]
  float* qs = qc + 56;                      // [56]
  float* xc = qs + 56;                      // [14]
  float* xs = xc + 14;                      // [14]

  const int b = blockIdx.x;
  const int tid = threadIdx.x;

  // ---- angles ----
  if (tid < NQ) {
    float sv, cv; sincosf(0.5f * x[b * NQ + tid], &sv, &cv);
    xc[tid] = cv; xs[tid] = sv;
  } else if (tid >= 64 && tid < 64 + NLAYERS * NQ) {
    const int k = tid - 64;
    float sv, cv; sincosf(0.5f * qp[k], &sv, &cv);
    qc[k] = cv; qs[k] = sv;
  }
  __syncthreads();

  // ---- closed-form state at L1-B entry (scratch aliases Bc) ----
  float* Flo  = (float*)Bc;         // [32]
  float* psi  = Flo + 32;           // [32]
  float* PsiR = psi + 32;           // [32]
  float* PsiI = PsiR + 32;          // [32]
  if (tid < 32) {
    float f = 1.f;
#pragma unroll
    for (int j = 0; j < 5; ++j) f *= ((tid >> j) & 1) ? xs[5 + j] : xc[5 + j];
    Flo[tid] = f;
  } else if (tid < 64) {
    const int k = tid - 32;
    float f = 1.f;
#pragma unroll
    for (int j = 0; j < 5; ++j) f *= ((k >> j) & 1) ? xs[j] : xc[j];
    psi[k] = f;
  }
  __syncthreads();
  if (tid < 32) {   // Psi = U_L1A * psi
    const float c0 = qc[0], c1 = qc[1], c2 = qc[2], c3 = qc[3], c4 = qc[4];
    const float s0 = qs[0], s1 = qs[1], s2 = qs[2], s3 = qs[3], s4 = qs[4];
    const int a = finv5(tid);
    float ar = 0.f, ai = 0.f;
    for (int k = 0; k < 32; ++k) {
      const int d = a ^ k;
      float mag = ((d & 1) ? s0 : c0) * ((d & 2) ? s1 : c1);
      mag *= ((d & 4) ? s2 : c2) * ((d & 8) ? s3 : c3);
      mag *= ((d & 16) ? s4 : c4);
      mag *= psi[k];
      const int t = __popc(d) & 3;
      if (t == 0) ar += mag; else if (t == 1) ai -= mag;
      else if (t == 2) ar -= mag; else ai += mag;
    }
    PsiR[tid] = ar; PsiI[tid] = ai;
  }
  __syncthreads();
  {  // state at L1-B entry: amp(e = tid*32 + k) -> F32 layout
    float fhi = 1.f;
#pragma unroll
    for (int j = 0; j < 4; ++j) fhi *= ((tid >> j) & 1) ? xs[10 + j] : xc[10 + j];
    const float cr = fhi * PsiR[tid >> 4], ci = fhi * PsiI[tid >> 4];
    const int t = tid >> 4;
    const int sz = swz(t);
    float Fl[32];
#pragma unroll
    for (int j = 0; j < 32; ++j) Fl[j] = Flo[j];
    __syncthreads();   // scratch reads done; Bc free for builds
#pragma unroll
    for (int kb = 0; kb < 4; ++kb) {
      f16x8 hr, hi;
#pragma unroll
      for (int j = 0; j < 8; ++j) {
        const float F = Fl[8 * kb + j];
        hr[j] = (f16)(F * cr);
        hi[j] = (f16)(F * ci);
      }
      const int pb = t * 512 + ((128 * kb + 8 * (tid & 15)) ^ sz);
      *(f16x8*)(reP + pb) = hr;
      *(f16x8*)(imP + pb) = hi;
    }
  }
  build32(Bc, qc, qs, 0 * NQ + 5, tid);   // U(L1-B); scratch reads already fenced
  __syncthreads();

  // ---- 11 GEMM passes, builds as separate steps (R8 structure) ----
  pass32<true, true>(reP, imP, Bc, tid);          __syncthreads(); // L1-B
  buildC(Bc, qc, qs, 0 * NQ + 10, tid);           __syncthreads();
  passC<false>(reP, imP, Bc, tid, nullptr);       __syncthreads(); // L1-C
#pragma unroll
  for (int l = 1; l < NLAYERS; ++l) {
    build32(Bc, qc, qs, l * NQ + 0, tid);         __syncthreads();
    pass32<false, false>(reP, imP, Bc, tid);      __syncthreads(); // A
    build32(Bc, qc, qs, l * NQ + 5, tid);         __syncthreads();
    pass32<true, true>(reP, imP, Bc, tid);        __syncthreads(); // B
    buildC(Bc, qc, qs, l * NQ + 10, tid);         __syncthreads();
    if (l < NLAYERS - 1) {
      passC<false>(reP, imP, Bc, tid, nullptr);   __syncthreads(); // C
    }
  }

  float zloc[NQ];
#pragma unroll
  for (int w = 0; w < NQ; ++w) zloc[w] = 0.f;
  passC<true>(reP, imP, Bc, tid, zloc);           // L4-C fused readout
  __syncthreads();

  // ---- reduce + linear head (zpart aliases Bc) ----
  float* zpart = (float*)Bc;         // [8*14]
  float* zbuf  = zpart + 112;        // [14]
#pragma unroll
  for (int w = 0; w < NQ; ++w) {
#pragma unroll
    for (int off = 32; off > 0; off >>= 1)
      zloc[w] += __shfl_down(zloc[w], off, 64);
  }
  const int wave = tid >> 6, lane = tid & 63;
  if (lane == 0) {
#pragma unroll
    for (int w = 0; w < NQ; ++w) zpart[wave * NQ + w] = zloc[w];
  }
  __syncthreads();
  if (tid < NQ) {
    float a = 0.f;
#pragma unroll
    for (int v = 0; v < 8; ++v) a += zpart[v * NQ + tid];
    zbuf[tid] = a;
  }
  __syncthreads();
  if (tid < NCLASSES) {
    float acc = fcb[tid];
#pragma unroll
    for (int w = 0; w < NQ; ++w) acc = fmaf(zbuf[w], fcw[tid * NQ + w], acc);
    out[b * NCLASSES + tid] = acc;
  }
}

extern "C" void kernel_launch(void* const* d_in, const int* in_sizes, int n_in,
                              void* d_out, int out_size, void* d_ws, size_t ws_size,
                              hipStream_t stream) {
  const float* x   = (const float*)d_in[0];
  const float* qp  = (const float*)d_in[1];
  const float* fcw = (const float*)d_in[2];
  const float* fcb = (const float*)d_in[3];
  float* out = (float*)d_out;
  const int B = in_sizes[0] / NQ;

  const size_t shmem = (size_t)(2 * 16384 + 2048) * sizeof(f16)
                     + (size_t)(56 + 56 + 14 + 14) * sizeof(float);   // 70192 B
  (void)hipFuncSetAttribute((const void*)qsim_kernel,
                            hipFuncAttributeMaxDynamicSharedMemorySize, (int)shmem);
  qsim_kernel<<<B, BLOCK, shmem, stream>>>(x, qp, fcw, fcb, out);
}